// Round 2
// baseline (375.882 us; speedup 1.0000x reference)
//
#include <hip/hip_runtime.h>
#include <math.h>

#define HH 256
#define WW 256
#define EPS2D 1e-4f
#define MAXN 1024

// Record layout (12 floats = 3 x float4 per gaussian, sorted front-to-back):
// [mx, my, qa, qb] [qc, lk, cr, cg] [cb, pad, pad, pad]
// alpha = exp2( qa*dx*dx + qb*dx*dy + qc*dy*dy + lk )

__global__ __launch_bounds__(MAXN) void prep_kernel(
    const float* __restrict__ means3D, const float* __restrict__ covs3d,
    const float* __restrict__ colors,  const float* __restrict__ opac,
    const float* __restrict__ Km,      const float* __restrict__ Rm,
    const float* __restrict__ tv,      float* __restrict__ rec, int n)
{
    __shared__ float s_depth[MAXN];
    int i = threadIdx.x;

    float mx = 0.f, my = 0.f, qa = 0.f, qb = 0.f, qc = 0.f, lk = 0.f;
    float cr = 0.f, cg = 0.f, cb = 0.f, depth = 1e30f;

    if (i < n) {
        float X = means3D[3*i+0], Y = means3D[3*i+1], Z = means3D[3*i+2];
        float R00=Rm[0],R01=Rm[1],R02=Rm[2];
        float R10=Rm[3],R11=Rm[4],R12=Rm[5];
        float R20=Rm[6],R21=Rm[7],R22=Rm[8];
        float t0=tv[0], t1=tv[1], t2=tv[2];

        float cx = R00*X + R01*Y + R02*Z + t0;
        float cy = R10*X + R11*Y + R12*Z + t1;
        float cz = R20*X + R21*Y + R22*Z + t2;
        depth = fmaxf(cz, 1.0f);

        float K00=Km[0],K01=Km[1],K02=Km[2];
        float K10=Km[3],K11=Km[4],K12=Km[5];
        float K20=Km[6],K21=Km[7],K22=Km[8];
        float sx = K00*cx + K01*cy + K02*cz;
        float sy = K10*cx + K11*cy + K12*cz;
        float sz = K20*cx + K21*cy + K22*cz;
        mx = sx / sz;
        my = sy / sz;

        float fx = K00, fy = K11;
        float invz  = 1.0f / cz;
        float invz2 = invz * invz;
        float j00 =  fx * invz;
        float j02 = -fx * cx * invz2;
        float j11 =  fy * invz;
        float j12 = -fy * cy * invz2;

        const float* S = covs3d + 9*i;
        float S00=S[0],S01=S[1],S02=S[2];
        float S10=S[3],S11=S[4],S12=S[5];
        float S20=S[6],S21=S[7],S22=S[8];

        // M = R * S
        float M00 = R00*S00 + R01*S10 + R02*S20;
        float M01 = R00*S01 + R01*S11 + R02*S21;
        float M02 = R00*S02 + R01*S12 + R02*S22;
        float M10 = R10*S00 + R11*S10 + R12*S20;
        float M11 = R10*S01 + R11*S11 + R12*S21;
        float M12 = R10*S02 + R11*S12 + R12*S22;
        float M20 = R20*S00 + R21*S10 + R22*S20;
        float M21 = R20*S01 + R21*S11 + R22*S21;
        float M22 = R20*S02 + R21*S12 + R22*S22;
        // C = M * R^T  (symmetric)
        float C00 = M00*R00 + M01*R01 + M02*R02;
        float C01 = M00*R10 + M01*R11 + M02*R12;
        float C02 = M00*R20 + M01*R21 + M02*R22;
        float C11 = M10*R10 + M11*R11 + M12*R12;
        float C12 = M10*R20 + M11*R21 + M12*R22;
        float C22 = M20*R20 + M21*R21 + M22*R22;

        // cov2D = J C J^T + eps*I, J = [[j00,0,j02],[0,j11,j12]]
        float a_ = j00*j00*C00 + 2.0f*j00*j02*C02 + j02*j02*C22 + EPS2D;
        float b_ = j00*j11*C01 + j00*j12*C02 + j02*j11*C12 + j02*j12*C22;
        float c_ = j11*j11*C11 + 2.0f*j11*j12*C12 + j12*j12*C22 + EPS2D;

        float det = a_ * c_ - b_ * b_;
        float ia =  c_ / det;
        float ib = -b_ / det;
        float ic =  a_ / det;
        float norm = 1.0f / (6.283185307179586f * sqrtf(det));

        bool valid = (depth > 1.0f) && (depth < 50.0f);
        float k = opac[i] * norm * (valid ? 1.0f : 0.0f);

        const float NL = -0.72134752044448170368f; // -0.5 * log2(e)
        qa = NL * ia;
        qb = 2.0f * NL * ib;
        qc = NL * ic;
        lk = log2f(k);   // -inf when k==0 -> alpha = 0

        cr = colors[3*i+0];
        cg = colors[3*i+1];
        cb = colors[3*i+2];

        s_depth[i] = depth;
    } else {
        s_depth[i] = 1e30f;
    }
    __syncthreads();

    if (i < n) {
        // stable rank: # of j that sort strictly before i
        int rank = 0;
        for (int j = 0; j < n; ++j) {
            float dj = s_depth[j];
            rank += (dj < depth || (dj == depth && j < i)) ? 1 : 0;
        }
        float4* out4 = (float4*)rec;
        out4[3*rank+0] = make_float4(mx, my, qa, qb);
        out4[3*rank+1] = make_float4(qc, lk, cr, cg);
        out4[3*rank+2] = make_float4(cb, 0.f, 0.f, 0.f);
    }
}

__global__ __launch_bounds__(256) void render_kernel(
    const float* __restrict__ rec, float* __restrict__ out, int n)
{
    int p = blockIdx.x * blockDim.x + threadIdx.x;
    float px = (float)(p & (WW - 1));
    float py = (float)(p >> 8);          // W == 256

    const float4* g4 = (const float4*)rec;

    float T = 1.0f, r = 0.f, g = 0.f, b = 0.f;
    for (int j = 0; j < n; ++j) {
        float4 g0 = g4[3*j+0];
        float4 g1 = g4[3*j+1];
        float  cbl = rec[12*j+8];

        float dx = px - g0.x;
        float dy = py - g0.y;
        // q = qa*dx*dx + qb*dx*dy + qc*dy*dy + lk
        float q = fmaf(fmaf(g0.z, dx, g0.w * dy), dx,
                       fmaf(g1.x * dy, dy, g1.y));
        float e = exp2f(q);      // alpha (k folded into exponent)
        float w = T * e;
        r = fmaf(w, g1.z, r);
        g = fmaf(w, g1.w, g);
        b = fmaf(w, cbl, b);
        T -= w;                  // T *= (1 - alpha)

        if ((j & 31) == 31) {
            if (__all(T < 1e-6f)) break;   // remaining contribution <= T <= 1e-6
        }
    }

    out[3*p+0] = r;
    out[3*p+1] = g;
    out[3*p+2] = b;
}

extern "C" void kernel_launch(void* const* d_in, const int* in_sizes, int n_in,
                              void* d_out, int out_size, void* d_ws, size_t ws_size,
                              hipStream_t stream)
{
    const float* means3D = (const float*)d_in[0];
    const float* covs3d  = (const float*)d_in[1];
    const float* colors  = (const float*)d_in[2];
    const float* opac    = (const float*)d_in[3];
    const float* Km      = (const float*)d_in[4];
    const float* Rm      = (const float*)d_in[5];
    const float* tv      = (const float*)d_in[6];
    int n = in_sizes[3];                 // opacities count == N
    if (n > MAXN) n = MAXN;

    float* rec = (float*)d_ws;           // 12 floats per gaussian (48 KB @ N=1024)

    hipLaunchKernelGGL(prep_kernel, dim3(1), dim3(MAXN), 0, stream,
                       means3D, covs3d, colors, opac, Km, Rm, tv, rec, n);

    int npix = HH * WW;
    hipLaunchKernelGGL(render_kernel, dim3(npix / 256), dim3(256), 0, stream,
                       rec, (float*)d_out, n);
}

// Round 3
// 90.847 us; speedup vs baseline: 4.1375x; 4.1375x over previous
//
#include <hip/hip_runtime.h>
#include <math.h>

#define HH 256
#define WW 256
#define EPS2D 1e-4f
#define MAXN 1024
#define NPIX (HH*WW)

// Record layout (12 floats = 3 x float4 per gaussian, sorted front-to-back):
// [mx, my, qa, qb] [qc, lk, cr, cg] [cb, pad, pad, pad]
// alpha = exp2( qa*dx*dx + qb*dx*dy + qc*dy*dy + lk )

__global__ __launch_bounds__(MAXN) void prep_kernel(
    const float* __restrict__ means3D, const float* __restrict__ covs3d,
    const float* __restrict__ colors,  const float* __restrict__ opac,
    const float* __restrict__ Km,      const float* __restrict__ Rm,
    const float* __restrict__ tv,      float* __restrict__ rec, int n)
{
    __shared__ float s_depth[MAXN];
    int i = threadIdx.x;

    float mx = 0.f, my = 0.f, qa = 0.f, qb = 0.f, qc = 0.f, lk = 0.f;
    float cr = 0.f, cg = 0.f, cb = 0.f, depth = 1e30f;

    if (i < n) {
        float X = means3D[3*i+0], Y = means3D[3*i+1], Z = means3D[3*i+2];
        float R00=Rm[0],R01=Rm[1],R02=Rm[2];
        float R10=Rm[3],R11=Rm[4],R12=Rm[5];
        float R20=Rm[6],R21=Rm[7],R22=Rm[8];
        float t0=tv[0], t1=tv[1], t2=tv[2];

        float cx = R00*X + R01*Y + R02*Z + t0;
        float cy = R10*X + R11*Y + R12*Z + t1;
        float cz = R20*X + R21*Y + R22*Z + t2;
        depth = fmaxf(cz, 1.0f);

        float K00=Km[0],K01=Km[1],K02=Km[2];
        float K10=Km[3],K11=Km[4],K12=Km[5];
        float K20=Km[6],K21=Km[7],K22=Km[8];
        float sx = K00*cx + K01*cy + K02*cz;
        float sy = K10*cx + K11*cy + K12*cz;
        float sz = K20*cx + K21*cy + K22*cz;
        mx = sx / sz;
        my = sy / sz;

        float fx = K00, fy = K11;
        float invz  = 1.0f / cz;
        float invz2 = invz * invz;
        float j00 =  fx * invz;
        float j02 = -fx * cx * invz2;
        float j11 =  fy * invz;
        float j12 = -fy * cy * invz2;

        const float* S = covs3d + 9*i;
        float S00=S[0],S01=S[1],S02=S[2];
        float S10=S[3],S11=S[4],S12=S[5];
        float S20=S[6],S21=S[7],S22=S[8];

        // M = R * S
        float M00 = R00*S00 + R01*S10 + R02*S20;
        float M01 = R00*S01 + R01*S11 + R02*S21;
        float M02 = R00*S02 + R01*S12 + R02*S22;
        float M10 = R10*S00 + R11*S10 + R12*S20;
        float M11 = R10*S01 + R11*S11 + R12*S21;
        float M12 = R10*S02 + R11*S12 + R12*S22;
        float M20 = R20*S00 + R21*S10 + R22*S20;
        float M21 = R20*S01 + R21*S11 + R22*S21;
        float M22 = R20*S02 + R21*S12 + R22*S22;
        // C = M * R^T  (symmetric)
        float C00 = M00*R00 + M01*R01 + M02*R02;
        float C01 = M00*R10 + M01*R11 + M02*R12;
        float C02 = M00*R20 + M01*R21 + M02*R22;
        float C11 = M10*R10 + M11*R11 + M12*R12;
        float C12 = M10*R20 + M11*R21 + M12*R22;
        float C22 = M20*R20 + M21*R21 + M22*R22;

        // cov2D = J C J^T + eps*I, J = [[j00,0,j02],[0,j11,j12]]
        float a_ = j00*j00*C00 + 2.0f*j00*j02*C02 + j02*j02*C22 + EPS2D;
        float b_ = j00*j11*C01 + j00*j12*C02 + j02*j11*C12 + j02*j12*C22;
        float c_ = j11*j11*C11 + 2.0f*j11*j12*C12 + j12*j12*C22 + EPS2D;

        float det = a_ * c_ - b_ * b_;
        float ia =  c_ / det;
        float ib = -b_ / det;
        float ic =  a_ / det;
        float norm = 1.0f / (6.283185307179586f * sqrtf(det));

        bool valid = (depth > 1.0f) && (depth < 50.0f);
        float k = opac[i] * norm * (valid ? 1.0f : 0.0f);

        const float NL = -0.72134752044448170368f; // -0.5 * log2(e)
        qa = NL * ia;
        qb = 2.0f * NL * ib;
        qc = NL * ic;
        lk = log2f(k);   // -inf when k==0 -> alpha = 0

        cr = colors[3*i+0];
        cg = colors[3*i+1];
        cb = colors[3*i+2];

        s_depth[i] = depth;
    } else {
        s_depth[i] = 1e30f;
    }
    __syncthreads();

    if (i < n) {
        // stable rank: # of j that sort strictly before i (float4-vectorized)
        int rank = 0;
        const float4* d4 = (const float4*)s_depth;
        int n4 = n >> 2;
        for (int j4 = 0; j4 < n4; ++j4) {
            float4 v = d4[j4];
            int j = 4*j4;
            rank += (v.x < depth || (v.x == depth && j+0 < i)) ? 1 : 0;
            rank += (v.y < depth || (v.y == depth && j+1 < i)) ? 1 : 0;
            rank += (v.z < depth || (v.z == depth && j+2 < i)) ? 1 : 0;
            rank += (v.w < depth || (v.w == depth && j+3 < i)) ? 1 : 0;
        }
        for (int j = n4*4; j < n; ++j) {
            float dj = s_depth[j];
            rank += (dj < depth || (dj == depth && j < i)) ? 1 : 0;
        }
        float4* out4 = (float4*)rec;
        out4[3*rank+0] = make_float4(mx, my, qa, qb);
        out4[3*rank+1] = make_float4(qc, lk, cr, cg);
        out4[3*rank+2] = make_float4(cb, 0.f, 0.f, 0.f);
    }
}

// Segmented render: blockIdx.y = segment, processes gaussians [s*cnt, min(n,(s+1)*cnt))
// writes (r,g,b,T) partial per pixel per segment.
extern __shared__ float4 lds4[];

__global__ __launch_bounds__(256) void render_seg_kernel(
    const float4* __restrict__ rec4, float4* __restrict__ part,
    int n, int cnt)
{
    int s  = blockIdx.y;
    int g0 = s * cnt;
    int g1 = min(n, g0 + cnt);
    int m  = g1 - g0;

    for (int idx = threadIdx.x; idx < m*3; idx += 256)
        lds4[idx] = rec4[g0*3 + idx];
    __syncthreads();

    int p = blockIdx.x * 256 + threadIdx.x;
    float px = (float)(p & (WW - 1));
    float py = (float)(p >> 8);

    const float* ldsf = (const float*)lds4;

    float T = 1.0f, r = 0.f, g = 0.f, b = 0.f;
    for (int j = 0; j < m; ++j) {
        float4 v0 = lds4[3*j+0];
        float4 v1 = lds4[3*j+1];
        float  cb = ldsf[12*j+8];

        float dx = px - v0.x;
        float dy = py - v0.y;
        float q = fmaf(fmaf(v0.z, dx, v0.w * dy), dx,
                       fmaf(v1.x * dy, dy, v1.y));
        float e = __builtin_amdgcn_exp2f(q);
        float w = T * e;
        r = fmaf(w, v1.z, r);
        g = fmaf(w, v1.w, g);
        b = fmaf(w, cb,  b);
        T -= w;

        if ((j & 63) == 63) {
            if (__all(T < 1e-7f)) break;   // residual within this segment <= T
        }
    }

    part[s * NPIX + p] = make_float4(r, g, b, T);
}

// Fallback: direct render (seg==1, no partials buffer needed)
__global__ __launch_bounds__(256) void render_direct_kernel(
    const float4* __restrict__ rec4, float* __restrict__ out, int n)
{
    for (int idx = threadIdx.x; idx < n*3; idx += 256)
        lds4[idx] = rec4[idx];
    __syncthreads();

    int p = blockIdx.x * 256 + threadIdx.x;
    float px = (float)(p & (WW - 1));
    float py = (float)(p >> 8);
    const float* ldsf = (const float*)lds4;

    float T = 1.0f, r = 0.f, g = 0.f, b = 0.f;
    for (int j = 0; j < n; ++j) {
        float4 v0 = lds4[3*j+0];
        float4 v1 = lds4[3*j+1];
        float  cb = ldsf[12*j+8];
        float dx = px - v0.x;
        float dy = py - v0.y;
        float q = fmaf(fmaf(v0.z, dx, v0.w * dy), dx,
                       fmaf(v1.x * dy, dy, v1.y));
        float e = __builtin_amdgcn_exp2f(q);
        float w = T * e;
        r = fmaf(w, v1.z, r);
        g = fmaf(w, v1.w, g);
        b = fmaf(w, cb,  b);
        T -= w;
        if ((j & 63) == 63) {
            if (__all(T < 1e-7f)) break;
        }
    }
    out[3*p+0] = r;
    out[3*p+1] = g;
    out[3*p+2] = b;
}

__global__ __launch_bounds__(256) void combine_kernel(
    const float4* __restrict__ part, float* __restrict__ out, int seg)
{
    int p = blockIdx.x * 256 + threadIdx.x;
    float r = 0.f, g = 0.f, b = 0.f, T = 1.0f;
    for (int s = 0; s < seg; ++s) {
        float4 v = part[s * NPIX + p];
        r = fmaf(T, v.x, r);
        g = fmaf(T, v.y, g);
        b = fmaf(T, v.z, b);
        T *= v.w;
    }
    out[3*p+0] = r;
    out[3*p+1] = g;
    out[3*p+2] = b;
}

extern "C" void kernel_launch(void* const* d_in, const int* in_sizes, int n_in,
                              void* d_out, int out_size, void* d_ws, size_t ws_size,
                              hipStream_t stream)
{
    const float* means3D = (const float*)d_in[0];
    const float* covs3d  = (const float*)d_in[1];
    const float* colors  = (const float*)d_in[2];
    const float* opac    = (const float*)d_in[3];
    const float* Km      = (const float*)d_in[4];
    const float* Rm      = (const float*)d_in[5];
    const float* tv      = (const float*)d_in[6];
    int n = in_sizes[3];                 // opacities count == N
    if (n > MAXN) n = MAXN;

    float* rec = (float*)d_ws;           // 12 floats per gaussian (48 KB @ N=1024)

    hipLaunchKernelGGL(prep_kernel, dim3(1), dim3(MAXN), 0, stream,
                       means3D, covs3d, colors, opac, Km, Rm, tv, rec, n);

    const size_t base = 64 * 1024;
    int seg = 1;
    if      (ws_size >= base + (size_t)8 * NPIX * 16) seg = 8;
    else if (ws_size >= base + (size_t)4 * NPIX * 16) seg = 4;
    else if (ws_size >= base + (size_t)2 * NPIX * 16) seg = 2;

    if (seg > 1) {
        int cnt = (n + seg - 1) / seg;
        float4* part = (float4*)((char*)d_ws + base);
        size_t shbytes = (size_t)cnt * 48;
        hipLaunchKernelGGL(render_seg_kernel, dim3(NPIX/256, seg), dim3(256),
                           shbytes, stream, (const float4*)rec, part, n, cnt);
        hipLaunchKernelGGL(combine_kernel, dim3(NPIX/256), dim3(256), 0, stream,
                           part, (float*)d_out, seg);
    } else {
        size_t shbytes = (size_t)n * 48;
        hipLaunchKernelGGL(render_direct_kernel, dim3(NPIX/256), dim3(256),
                           shbytes, stream, (const float4*)rec, (float*)d_out, n);
    }
}

// Round 4
// 62.022 us; speedup vs baseline: 6.0605x; 1.4648x over previous
//
#include <hip/hip_runtime.h>
#include <math.h>

#define HH 256
#define WW 256
#define EPS2D 1e-4f
#define MAXN 1024
#define NPIX (HH*WW)
#define CULL_THR 30.0f   // keep gaussian iff somewhere in block q >= -30 (alpha >= 2^-30)

// Record: 3 x float4 per gaussian, depth-sorted front-to-back:
// [mx, my, qa, qb] [qc, lk, cr, cg] [cb, 0, 0, 0]
// alpha = exp2( qa*dx*dx + qb*dx*dy + qc*dy*dy + lk ),  qa,qc < 0

__global__ __launch_bounds__(64) void prep_kernel(
    const float* __restrict__ means3D, const float* __restrict__ covs3d,
    const float* __restrict__ colors,  const float* __restrict__ opac,
    const float* __restrict__ Km,      const float* __restrict__ Rm,
    const float* __restrict__ tv,      float4* __restrict__ rec, int n)
{
    __shared__ float s_depth[MAXN];
    int t = threadIdx.x;

    float R00=Rm[0],R01=Rm[1],R02=Rm[2];
    float R10=Rm[3],R11=Rm[4],R12=Rm[5];
    float R20=Rm[6],R21=Rm[7],R22=Rm[8];
    float t0=tv[0], t1=tv[1], t2=tv[2];

    // Phase A: every block computes ALL depths (cheap: 3 FMA each)
    for (int g = t; g < MAXN; g += 64) {
        float d = 1e30f;
        if (g < n) {
            float X=means3D[3*g+0], Y=means3D[3*g+1], Z=means3D[3*g+2];
            float cz = R20*X + R21*Y + R22*Z + t2;
            d = fmaxf(cz, 1.0f);
        }
        s_depth[g] = d;
    }
    __syncthreads();

    // Phase B: this block's 64 gaussians: full projection + rank + scatter
    int i = blockIdx.x * 64 + t;
    if (i >= n) return;

    float X = means3D[3*i+0], Y = means3D[3*i+1], Z = means3D[3*i+2];
    float cx = R00*X + R01*Y + R02*Z + t0;
    float cy = R10*X + R11*Y + R12*Z + t1;
    float cz = R20*X + R21*Y + R22*Z + t2;
    float depth = s_depth[i];

    float K00=Km[0],K01=Km[1],K02=Km[2];
    float K10=Km[3],K11=Km[4],K12=Km[5];
    float K20=Km[6],K21=Km[7],K22=Km[8];
    float sx = K00*cx + K01*cy + K02*cz;
    float sy = K10*cx + K11*cy + K12*cz;
    float sz = K20*cx + K21*cy + K22*cz;
    float mx = sx / sz;
    float my = sy / sz;

    float fx = K00, fy = K11;
    float invz  = 1.0f / cz;
    float invz2 = invz * invz;
    float j00 =  fx * invz;
    float j02 = -fx * cx * invz2;
    float j11 =  fy * invz;
    float j12 = -fy * cy * invz2;

    const float* S = covs3d + 9*i;
    float S00=S[0],S01=S[1],S02=S[2];
    float S10=S[3],S11=S[4],S12=S[5];
    float S20=S[6],S21=S[7],S22=S[8];

    float M00 = R00*S00 + R01*S10 + R02*S20;
    float M01 = R00*S01 + R01*S11 + R02*S21;
    float M02 = R00*S02 + R01*S12 + R02*S22;
    float M10 = R10*S00 + R11*S10 + R12*S20;
    float M11 = R10*S01 + R11*S11 + R12*S21;
    float M12 = R10*S02 + R11*S12 + R12*S22;
    float M20 = R20*S00 + R21*S10 + R22*S20;
    float M21 = R20*S01 + R21*S11 + R22*S21;
    float M22 = R20*S02 + R21*S12 + R22*S22;
    float C00 = M00*R00 + M01*R01 + M02*R02;
    float C01 = M00*R10 + M01*R11 + M02*R12;
    float C02 = M00*R20 + M01*R21 + M02*R22;
    float C11 = M10*R10 + M11*R11 + M12*R12;
    float C12 = M10*R20 + M11*R21 + M12*R22;
    float C22 = M20*R20 + M21*R21 + M22*R22;

    float a_ = j00*j00*C00 + 2.0f*j00*j02*C02 + j02*j02*C22 + EPS2D;
    float b_ = j00*j11*C01 + j00*j12*C02 + j02*j11*C12 + j02*j12*C22;
    float c_ = j11*j11*C11 + 2.0f*j11*j12*C12 + j12*j12*C22 + EPS2D;

    float det = a_ * c_ - b_ * b_;
    float ia =  c_ / det;
    float ib = -b_ / det;
    float ic =  a_ / det;
    float norm = 1.0f / (6.283185307179586f * sqrtf(det));

    bool valid = (depth > 1.0f) && (depth < 50.0f);
    float k = opac[i] * norm * (valid ? 1.0f : 0.0f);

    const float NL = -0.72134752044448170368f; // -0.5 * log2(e)
    float qa = NL * ia;
    float qb = 2.0f * NL * ib;
    float qc = NL * ic;
    float lk = log2f(k);   // -inf when k==0

    float cr = colors[3*i+0];
    float cg = colors[3*i+1];
    float cb = colors[3*i+2];

    // stable rank over LDS depths (float4-vectorized)
    int rank = 0;
    const float4* d4 = (const float4*)s_depth;
    int n4 = n >> 2;
    for (int j4 = 0; j4 < n4; ++j4) {
        float4 v = d4[j4];
        int j = 4*j4;
        rank += (v.x < depth || (v.x == depth && j+0 < i)) ? 1 : 0;
        rank += (v.y < depth || (v.y == depth && j+1 < i)) ? 1 : 0;
        rank += (v.z < depth || (v.z == depth && j+2 < i)) ? 1 : 0;
        rank += (v.w < depth || (v.w == depth && j+3 < i)) ? 1 : 0;
    }
    for (int j = n4*4; j < n; ++j) {
        float dj = s_depth[j];
        rank += (dj < depth || (dj == depth && j < i)) ? 1 : 0;
    }

    rec[3*rank+0] = make_float4(mx, my, qa, qb);
    rec[3*rank+1] = make_float4(qc, lk, cr, cg);
    rec[3*rank+2] = make_float4(cb, 0.f, 0.f, 0.f);
}

// Render: grid (NPIX/1024, seg). Block = 256 threads, 4 waves = 4 rows,
// each thread 4 pixels (x = lane + 64*i). Cull + stable-compact + composite.
extern __shared__ char smem[];

__global__ __launch_bounds__(256) void render_kernel(
    const float4* __restrict__ rec, float4* __restrict__ part,
    float* __restrict__ out, int n, int cnt, int direct)
{
    int s  = blockIdx.y;
    int gb = s * cnt;
    int m  = min(n, gb + cnt) - gb;
    if (m < 0) m = 0;

    float4* s_rec = (float4*)smem;                       // 3*cnt float4
    int*    s_idx = (int*)(smem + (size_t)cnt * 48);     // cnt ints
    __shared__ int s_w[4];
    __shared__ int s_total;

    int t = threadIdx.x, lane = t & 63, wid = t >> 6;
    if (t == 0) s_total = 0;
    __syncthreads();

    float ylo = (float)(blockIdx.x * 4);
    float yhi = ylo + 3.0f;

    // ---- cull + order-stable compaction ----
    for (int c = 0; c < m; c += 256) {
        int j = c + t;
        bool keep = false;
        if (j < m) {
            float4 v0 = rec[3*(gb+j)+0];
            float4 v1 = rec[3*(gb+j)+1];
            float qa = v0.z, qb = v0.w, qc = v1.x, lk = v1.y;
            float cc = lk + CULL_THR;
            if (cc > 0.0f) {
                float dpp = fmaf(4.0f*qa, qc, -qb*qb);   // 4*qa*qc - qb^2 > 0
                float inv = cc / dpp;
                float dxe = sqrtf(fmaxf(-4.0f*qc*inv, 0.0f));
                float dye = sqrtf(fmaxf(-4.0f*qa*inv, 0.0f));
                keep = (v0.x + dxe >= 0.0f)  && (v0.x - dxe <= 255.0f) &&
                       (v0.y + dye >= ylo)   && (v0.y - dye <= yhi);
            }
        }
        unsigned long long mk = __ballot(keep);
        int pre = __popcll(mk & ((1ull << lane) - 1ull));
        if (lane == 0) s_w[wid] = __popcll(mk);
        __syncthreads();
        int base = s_total;
        for (int w = 0; w < wid; ++w) base += s_w[w];
        if (keep) s_idx[base + pre] = j;
        __syncthreads();
        if (t == 0) s_total += s_w[0] + s_w[1] + s_w[2] + s_w[3];
        __syncthreads();
    }
    int sc = s_total;

    // ---- stage survivor records compacted into LDS ----
    for (int k = t; k < sc; k += 256) {
        int j = s_idx[k];
        s_rec[3*k+0] = rec[3*(gb+j)+0];
        s_rec[3*k+1] = rec[3*(gb+j)+1];
        s_rec[3*k+2] = rec[3*(gb+j)+2];
    }
    __syncthreads();

    const float* s_f = (const float*)s_rec;
    float pyf   = (float)(blockIdx.x * 4 + wid);
    float lanef = (float)lane;

    float T0=1.f,T1=1.f,T2=1.f,T3=1.f;
    float r0=0.f,r1=0.f,r2=0.f,r3=0.f;
    float g0=0.f,g1=0.f,g2=0.f,g3=0.f;
    float b0=0.f,b1=0.f,b2=0.f,b3=0.f;

    for (int k = 0; k < sc; ++k) {
        float4 v0 = s_rec[3*k+0];
        float4 v1 = s_rec[3*k+1];
        float  cb = s_f[12*k+8];

        float dy  = pyf - v0.y;
        float vb  = v0.w * dy;                   // qb*dy
        float u   = fmaf(v1.x * dy, dy, v1.y);   // qc*dy^2 + lk
        float dx0 = lanef - v0.x;

        {
            float dx = dx0;
            float q = fmaf(fmaf(v0.z, dx, vb), dx, u);
            float w = T0 * __builtin_amdgcn_exp2f(q);
            r0 = fmaf(w, v1.z, r0); g0 = fmaf(w, v1.w, g0); b0 = fmaf(w, cb, b0); T0 -= w;
        }
        {
            float dx = dx0 + 64.0f;
            float q = fmaf(fmaf(v0.z, dx, vb), dx, u);
            float w = T1 * __builtin_amdgcn_exp2f(q);
            r1 = fmaf(w, v1.z, r1); g1 = fmaf(w, v1.w, g1); b1 = fmaf(w, cb, b1); T1 -= w;
        }
        {
            float dx = dx0 + 128.0f;
            float q = fmaf(fmaf(v0.z, dx, vb), dx, u);
            float w = T2 * __builtin_amdgcn_exp2f(q);
            r2 = fmaf(w, v1.z, r2); g2 = fmaf(w, v1.w, g2); b2 = fmaf(w, cb, b2); T2 -= w;
        }
        {
            float dx = dx0 + 192.0f;
            float q = fmaf(fmaf(v0.z, dx, vb), dx, u);
            float w = T3 * __builtin_amdgcn_exp2f(q);
            r3 = fmaf(w, v1.z, r3); g3 = fmaf(w, v1.w, g3); b3 = fmaf(w, cb, b3); T3 -= w;
        }

        if ((k & 15) == 15) {
            float tm = fmaxf(fmaxf(T0, T1), fmaxf(T2, T3));
            if (__all(tm < 1e-7f)) break;
        }
    }

    int pbase = blockIdx.x * 1024 + wid * 256 + lane;   // row*256 + x
    if (direct) {
        out[3*(pbase+  0)+0]=r0; out[3*(pbase+  0)+1]=g0; out[3*(pbase+  0)+2]=b0;
        out[3*(pbase+ 64)+0]=r1; out[3*(pbase+ 64)+1]=g1; out[3*(pbase+ 64)+2]=b1;
        out[3*(pbase+128)+0]=r2; out[3*(pbase+128)+1]=g2; out[3*(pbase+128)+2]=b2;
        out[3*(pbase+192)+0]=r3; out[3*(pbase+192)+1]=g3; out[3*(pbase+192)+2]=b3;
    } else {
        part[s*NPIX + pbase +   0] = make_float4(r0, g0, b0, T0);
        part[s*NPIX + pbase +  64] = make_float4(r1, g1, b1, T1);
        part[s*NPIX + pbase + 128] = make_float4(r2, g2, b2, T2);
        part[s*NPIX + pbase + 192] = make_float4(r3, g3, b3, T3);
    }
}

__global__ __launch_bounds__(256) void combine_kernel(
    const float4* __restrict__ part, float* __restrict__ out, int seg)
{
    int p = blockIdx.x * 256 + threadIdx.x;
    float r = 0.f, g = 0.f, b = 0.f, T = 1.0f;
    for (int s = 0; s < seg; ++s) {
        float4 v = part[s * NPIX + p];
        r = fmaf(T, v.x, r);
        g = fmaf(T, v.y, g);
        b = fmaf(T, v.z, b);
        T *= v.w;
    }
    out[3*p+0] = r;
    out[3*p+1] = g;
    out[3*p+2] = b;
}

extern "C" void kernel_launch(void* const* d_in, const int* in_sizes, int n_in,
                              void* d_out, int out_size, void* d_ws, size_t ws_size,
                              hipStream_t stream)
{
    const float* means3D = (const float*)d_in[0];
    const float* covs3d  = (const float*)d_in[1];
    const float* colors  = (const float*)d_in[2];
    const float* opac    = (const float*)d_in[3];
    const float* Km      = (const float*)d_in[4];
    const float* Rm      = (const float*)d_in[5];
    const float* tv      = (const float*)d_in[6];
    int n = in_sizes[3];
    if (n > MAXN) n = MAXN;

    float4* rec = (float4*)d_ws;                 // 48 KB max
    const size_t base = 64 * 1024;

    int seg = 1, direct = 1;
    if      (ws_size >= base + (size_t)8 * NPIX * 16) { seg = 8; direct = 0; }
    else if (ws_size >= base + (size_t)4 * NPIX * 16) { seg = 4; direct = 0; }
    else if (ws_size >= base + (size_t)2 * NPIX * 16) { seg = 2; direct = 0; }
    else if (ws_size >= base + (size_t)1 * NPIX * 16) { seg = 1; direct = 0; }

    int cnt = (n + seg - 1) / seg;
    float4* part = (float4*)((char*)d_ws + base);
    size_t shbytes = (size_t)cnt * 48 + (size_t)cnt * 4;

    hipLaunchKernelGGL(prep_kernel, dim3(16), dim3(64), 0, stream,
                       means3D, covs3d, colors, opac, Km, Rm, tv, rec, n);

    hipLaunchKernelGGL(render_kernel, dim3(NPIX/1024, seg), dim3(256),
                       shbytes, stream, rec, part, (float*)d_out, n, cnt, direct);

    if (!direct) {
        hipLaunchKernelGGL(combine_kernel, dim3(NPIX/256), dim3(256), 0, stream,
                           part, (float*)d_out, seg);
    }
}